// Round 1
// baseline (859.671 us; speedup 1.0000x reference)
//
#include <hip/hip_runtime.h>

// ---------------------------------------------------------------------------
// DyHetGNN forward: grouped-by-etype bf16 MFMA GEMM chain.
// Slots: etype0 rows [0,cnt0), etype1 rows [S_TOP-cnt1, S_TOP); pads garbage.
// ---------------------------------------------------------------------------

#define M_EDGES 32768
#define S_TOP   32896          // M + 128, multiple of 128
#define GRID_U  257            // S_TOP / 128

typedef __bf16 bf16_t;
typedef __bf16 bf16x8 __attribute__((ext_vector_type(8)));
typedef float  f32x4  __attribute__((ext_vector_type(4)));

// weight buffer segment offsets (bf16 elements), all stored [n][k] (k=256 contig)
#define OFF_W1ST 0
#define OFF_W2ST 131072
#define OFF_W1GT 262144
#define OFF_W2GT 393216
#define OFF_WST  524288
#define OFF_WGT  589824
#define OFF_WXT  655360
#define OFF_WHT  917504
#define WBUF_ELEMS 1179648

__device__ __forceinline__ float sigm_f(float x) { return 1.f / (1.f + __expf(-x)); }
__device__ __forceinline__ float tanh_f(float x) {
  x = fminf(fmaxf(x, -15.f), 15.f);
  float e = __expf(2.f * x);
  return (e - 1.f) / (e + 1.f);
}
// XOR swizzle: spreads 128B-stride LDS rows across bank windows (read==write formula)
__device__ __forceinline__ unsigned short* swzp(unsigned short* base, int n, int byteoff) {
  return (unsigned short*)((char*)base + (byteoff ^ ((((n >> 3) ^ n) & 7) << 4)));
}

// ---------------- prep: weight transpose/cast + array init ----------------
__global__ __launch_bounds__(256)
void k_init(const float* __restrict__ W1s, const float* __restrict__ W2s,
            const float* __restrict__ W1g, const float* __restrict__ W2g,
            const float* __restrict__ Wsw, const float* __restrict__ Wgw,
            const float* __restrict__ Wx,  const float* __restrict__ Wh,
            bf16_t* __restrict__ wbuf, int* __restrict__ eid,
            int* __restrict__ srcn, int* __restrict__ dstn,
            float* __restrict__ dts, int* __restrict__ cnt)
{
  const int b = blockIdx.x, tid = threadIdx.x;
  if (b < 256) {                       // 64x64 transpose tiles, fp32 -> bf16
    const float* src; bf16_t* dst; int C_in, n0, k0;
    if (b < 128) {
      const int grp = b >> 5, e = (b >> 4) & 1, t16 = b & 15;
      const float* bases[4] = {W1s, W2s, W1g, W2g};
      src = bases[grp] + e * 65536;
      dst = wbuf + grp * 131072 + e * 65536;
      C_in = 256; n0 = (t16 >> 2) * 64; k0 = (t16 & 3) * 64;
    } else {
      const int b2 = b - 128, mat = b2 >> 6, t64 = b2 & 63;
      src = mat ? Wh : Wx;
      dst = wbuf + OFF_WXT + mat * 262144;
      C_in = 1024; n0 = (t64 >> 2) * 64; k0 = (t64 & 3) * 64;
    }
    __shared__ float tile[64][65];
    const int r = tid >> 2, cg = (tid & 3) * 16;
#pragma unroll
    for (int j = 0; j < 4; ++j) {
      float4 v = *(const float4*)(src + (k0 + r) * C_in + n0 + cg + 4 * j);
      tile[r][cg + 4 * j + 0] = v.x;
      tile[r][cg + 4 * j + 1] = v.y;
      tile[r][cg + 4 * j + 2] = v.z;
      tile[r][cg + 4 * j + 3] = v.w;
    }
    __syncthreads();
    const int c2 = tid >> 2, rg = (tid & 3) * 16;
#pragma unroll
    for (int j = 0; j < 16; ++j)
      dst[(n0 + c2) * 256 + k0 + rg + j] = (bf16_t)tile[rg + j][c2];
  } else {                             // plain casts + defaults
    const int idx0 = (b - 256) * 256 + tid;
    for (int i = idx0; i < 65536; i += 32768) {
      wbuf[OFF_WST + i] = (bf16_t)Wsw[i];   // Ws_w used transposed -> direct cast
      wbuf[OFF_WGT + i] = (bf16_t)Wgw[i];
    }
    for (int i = idx0; i < S_TOP; i += 32768) {
      eid[i] = -1; srcn[i] = 0; dstn[i] = 0; dts[i] = 0.f;
    }
    if (idx0 < 2) cnt[idx0] = 0;
  }
}

// ---------------- slot assignment ----------------
__global__ __launch_bounds__(256)
void k_slots(const int* __restrict__ etype, const int* __restrict__ src,
             const int* __restrict__ dst, const float* __restrict__ dt,
             int* __restrict__ cnt, int* __restrict__ eid, int* __restrict__ srcn,
             int* __restrict__ dstn, float* __restrict__ dts)
{
  const int m = blockIdx.x * 256 + threadIdx.x;
  if (m >= M_EDGES) return;
  const int e = etype[m];
  const int pos = atomicAdd(&cnt[e], 1);
  const int s = (e == 0) ? pos : (S_TOP - 1 - pos);
  eid[s] = m; srcn[s] = src[m]; dstn[s] = dst[m]; dts[s] = dt[m];
}

// ---------------- gather hid rows -> bf16 slot-ordered ----------------
__global__ __launch_bounds__(256)
void k_gather(const float* __restrict__ hid, const int* __restrict__ srcn,
              const int* __restrict__ dstn, bf16_t* __restrict__ Xs,
              bf16_t* __restrict__ Xg)
{
  const int s = blockIdx.x * 4 + (threadIdx.x >> 6);
  const int c = (threadIdx.x & 63) * 4;
  const int ns = srcn[s], ng = dstn[s];
  float4 vs = *(const float4*)(hid + (size_t)ns * 256 + c);
  float4 vg = *(const float4*)(hid + (size_t)ng * 256 + c);
  union { bf16_t h[4]; unsigned long long u; } pk;
  pk.h[0] = (bf16_t)vs.x; pk.h[1] = (bf16_t)vs.y; pk.h[2] = (bf16_t)vs.z; pk.h[3] = (bf16_t)vs.w;
  *(unsigned long long*)(Xs + s * 256 + c) = pk.u;
  pk.h[0] = (bf16_t)vg.x; pk.h[1] = (bf16_t)vg.y; pk.h[2] = (bf16_t)vg.z; pk.h[3] = (bf16_t)vg.w;
  *(unsigned long long*)(Xg + s * 256 + c) = pk.u;
}

// ---------------- unit GEMM: [S_TOP,256] @ [256,256] -------------------
// tile 128x256, 4 waves (each 128 rows x 64 cols), BK=64 LDS-staged B (n-major,
// swizzled), A frags direct from global. EPI: 0 relu, 1 bias+dot->ps,
// 2 bias+dot + a=sigmoid(ps+dot+pb+qb), 3 bias, 4 combine a*T+(1-a)*(acc+b).
template<int EPI, bool DUAL>
__global__ __launch_bounds__(256, 2)
void k_gemm(const bf16_t* __restrict__ A, const bf16_t* __restrict__ A2,
            const bf16_t* __restrict__ W0, const bf16_t* __restrict__ W1,
            const bf16_t* __restrict__ W20, const bf16_t* __restrict__ W21,
            const float* __restrict__ bias0, const float* __restrict__ bias1,
            bf16_t* __restrict__ Out, const int* __restrict__ cnt,
            const float* __restrict__ pq, float* __restrict__ ps,
            float* __restrict__ aarr, const float* __restrict__ sb0,
            const float* __restrict__ sb1, const bf16_t* __restrict__ Tmat)
{
  const int tid = threadIdx.x;
  const int w = tid >> 6, lane = tid & 63, lo = lane & 15, hi = lane >> 4;
  const int row0 = blockIdx.x * 128;
  const int cnt0 = cnt[0], cnt1 = cnt[1];
  const int cnt0r = (cnt0 + 127) & ~127;
  const int v1 = S_TOP - cnt1;
  if (row0 >= cnt0r && row0 + 128 <= v1) return;   // fully-dead block
  const int e = (row0 < cnt0r) ? 0 : 1;
  const float* bias = e ? bias1 : bias0;

  __shared__ unsigned short Bt[256 * 64];   // [n=256][kk=64] bf16, 32 KiB
  __shared__ float sdot[128];

  f32x4 acc[8][4];
  const f32x4 z4 = {0.f, 0.f, 0.f, 0.f};
#pragma unroll
  for (int rb = 0; rb < 8; ++rb)
#pragma unroll
    for (int tc = 0; tc < 4; ++tc) acc[rb][tc] = z4;

  const int nph = DUAL ? 2 : 1;
  for (int ph = 0; ph < nph; ++ph) {
    const bf16_t* Ap = (DUAL && ph) ? A2 : A;
    const bf16_t* Wp = (DUAL && ph) ? (e ? W21 : W20) : (e ? W1 : W0);
    for (int c = 0; c < 4; ++c) {               // K chunks of 64
      __syncthreads();
#pragma unroll
      for (int p = 0; p < 4; ++p) {             // stage B chunk
        const int n = (tid >> 2) + p * 64;
        const int i0 = tid & 3;
        const bf16_t* sp = Wp + n * 256 + c * 64;
        bf16x8 v0 = *(const bf16x8*)(sp + i0 * 8);
        bf16x8 v1 = *(const bf16x8*)(sp + 32 + i0 * 8);
        *(bf16x8*)swzp(Bt, n, n * 128 + i0 * 16) = v0;
        *(bf16x8*)swzp(Bt, n, n * 128 + 64 + i0 * 16) = v1;
      }
      __syncthreads();
#pragma unroll
      for (int ks = 0; ks < 2; ++ks) {          // two K=32 steps
        bf16x8 af[8];
#pragma unroll
        for (int rb = 0; rb < 8; ++rb)
          af[rb] = *(const bf16x8*)(Ap + (row0 + rb * 16 + lo) * 256 + c * 64 + ks * 32 + hi * 8);
#pragma unroll
        for (int tc = 0; tc < 4; ++tc) {
          const int n = w * 64 + tc * 16 + lo;
          bf16x8 bf = *(const bf16x8*)swzp(Bt, n, n * 128 + ks * 64 + hi * 16);
#pragma unroll
          for (int rb = 0; rb < 8; ++rb)
            acc[rb][tc] = __builtin_amdgcn_mfma_f32_16x16x32_bf16(af[rb], bf, acc[rb][tc], 0, 0, 0);
        }
      }
    }
  }

  if (EPI == 1 || EPI == 2) {
    if (tid < 128) sdot[tid] = 0.f;
    __syncthreads();
  }

  float dots[8][4];
#pragma unroll
  for (int rb = 0; rb < 8; ++rb)
#pragma unroll
    for (int i = 0; i < 4; ++i) dots[rb][i] = 0.f;

#pragma unroll
  for (int rb = 0; rb < 8; ++rb) {
#pragma unroll
    for (int tc = 0; tc < 4; ++tc) {
      const int col = w * 64 + tc * 16 + lo;
      const float bs = bias[col];
      const float pqv = (EPI == 1 || EPI == 2) ? pq[col] : 0.f;
      f32x4 v = acc[rb][tc];
#pragma unroll
      for (int i = 0; i < 4; ++i) {
        const int row = row0 + rb * 16 + hi * 4 + i;
        float val = v[i] + bs;
        if (EPI == 0) val = fmaxf(val, 0.f);
        if (EPI == 4) {
          const float av = aarr[row];
          const float tv = (float)Tmat[row * 256 + col];
          val = av * tv + (1.f - av) * val;
        }
        if (EPI == 1 || EPI == 2) dots[rb][i] += val * pqv;
        Out[row * 256 + col] = (bf16_t)val;
      }
    }
  }

  if (EPI == 1 || EPI == 2) {
#pragma unroll
    for (int rb = 0; rb < 8; ++rb) {
#pragma unroll
      for (int i = 0; i < 4; ++i) {
        float d = dots[rb][i];
        d += __shfl_xor(d, 1); d += __shfl_xor(d, 2);
        d += __shfl_xor(d, 4); d += __shfl_xor(d, 8);
        if (lo == 0) atomicAdd(&sdot[rb * 16 + hi * 4 + i], d);
      }
    }
    __syncthreads();
    if (tid < 128) {
      const int row = row0 + tid;
      if (EPI == 1) ps[row] = sdot[tid];
      else          aarr[row] = sigm_f(ps[row] + sdot[tid] + sb0[0] + sb1[0]);
    }
  }
}

// ---------------- elementwise LSTM + score (wave per row) ----------------
__global__ __launch_bounds__(256)
void k_lstm(const bf16_t* __restrict__ Gi, const bf16_t* __restrict__ Gf,
            const bf16_t* __restrict__ Gg, const bf16_t* __restrict__ Go,
            const float* __restrict__ cell, const int* __restrict__ eid,
            const int* __restrict__ dstn, const float* __restrict__ dts,
            const float* __restrict__ w_out, const float* __restrict__ b_out,
            const float* __restrict__ decay_w,
            float* __restrict__ outS, float* __restrict__ outH, float* __restrict__ outC)
{
  const int s = blockIdx.x * 4 + (threadIdx.x >> 6);
  const int lane = threadIdx.x & 63;
  const int m = eid[s];
  const int nd = dstn[s];
  const float dec = __expf(-fabsf(decay_w[0]) * dts[s]);
  float part = 0.f;
#pragma unroll
  for (int j = 0; j < 4; ++j) {
    const int cdim = j * 64 + lane;
    const float iv = (float)Gi[s * 256 + cdim];
    const float fv = (float)Gf[s * 256 + cdim];
    const float gv = (float)Gg[s * 256 + cdim];
    const float ov = (float)Go[s * 256 + cdim];
    const float cg = cell[(size_t)nd * 256 + cdim];
    const float cn = sigm_f(fv) * (cg * dec) + sigm_f(iv) * tanh_f(gv);
    const float hn = sigm_f(ov) * tanh_f(cn);
    if (m >= 0) {
      outH[(size_t)m * 256 + cdim] = hn;
      outC[(size_t)m * 256 + cdim] = cn;
    }
    part += hn * w_out[cdim];
  }
#pragma unroll
  for (int msk = 1; msk < 64; msk <<= 1) part += __shfl_xor(part, msk);
  if (lane == 0 && m >= 0) outS[m] = sigm_f(part + b_out[0]);
}

// ---------------------------------------------------------------------------
extern "C" void kernel_launch(void* const* d_in, const int* in_sizes, int n_in,
                              void* d_out, int out_size, void* d_ws, size_t ws_size,
                              hipStream_t stream)
{
  const int*   src     = (const int*)d_in[0];
  const int*   dst     = (const int*)d_in[1];
  const int*   etype   = (const int*)d_in[2];
  const float* dt      = (const float*)d_in[3];
  const float* hid     = (const float*)d_in[4];
  const float* cell    = (const float*)d_in[5];
  const float* W1s     = (const float*)d_in[6];
  const float* b1s     = (const float*)d_in[7];
  const float* W2s     = (const float*)d_in[8];
  const float* b2s     = (const float*)d_in[9];
  const float* W1g     = (const float*)d_in[10];
  const float* b1g     = (const float*)d_in[11];
  const float* W2g     = (const float*)d_in[12];
  const float* b2g     = (const float*)d_in[13];
  const float* p_w     = (const float*)d_in[14];
  const float* p_b     = (const float*)d_in[15];
  const float* q_w     = (const float*)d_in[16];
  const float* q_b     = (const float*)d_in[17];
  const float* Ws_w    = (const float*)d_in[18];
  const float* Ws_b    = (const float*)d_in[19];
  const float* Wg_w    = (const float*)d_in[20];
  const float* Wg_b    = (const float*)d_in[21];
  const float* Wx      = (const float*)d_in[22];
  const float* Wh      = (const float*)d_in[23];
  const float* b_lstm  = (const float*)d_in[24];
  const float* w_out   = (const float*)d_in[25];
  const float* b_out   = (const float*)d_in[26];
  const float* decay_w = (const float*)d_in[27];
  (void)in_sizes; (void)n_in; (void)out_size; (void)ws_size;

  char* p = (char*)d_ws;
  auto alloc = [&](size_t bytes) { char* r = p; p += (bytes + 255) & ~(size_t)255; return r; };
  const size_t SB = (size_t)S_TOP * 256 * sizeof(bf16_t);
  bf16_t* wbuf = (bf16_t*)alloc(WBUF_ELEMS * sizeof(bf16_t));
  bf16_t* Xs   = (bf16_t*)alloc(SB);
  bf16_t* Xg   = (bf16_t*)alloc(SB);
  bf16_t* B1   = (bf16_t*)alloc(SB);
  bf16_t* B2   = (bf16_t*)alloc(SB);
  bf16_t* B3   = (bf16_t*)alloc(SB);
  bf16_t* B4   = (bf16_t*)alloc(SB);
  float*  psb  = (float*)alloc(S_TOP * 4);
  float*  aarr = (float*)alloc(S_TOP * 4);
  int*    eid  = (int*)alloc(S_TOP * 4);
  int*    srcn = (int*)alloc(S_TOP * 4);
  int*    dstn = (int*)alloc(S_TOP * 4);
  float*  dts  = (float*)alloc(S_TOP * 4);
  int*    cnt  = (int*)alloc(256);
  // total ws use ~100 MiB

  float* outS = (float*)d_out;
  float* outH = outS + M_EDGES;
  float* outC = outH + (size_t)M_EDGES * 256;

  k_init<<<384, 256, 0, stream>>>(W1s, W2s, W1g, W2g, Ws_w, Wg_w, Wx, Wh,
                                  wbuf, eid, srcn, dstn, dts, cnt);
  k_slots<<<M_EDGES / 256, 256, 0, stream>>>(etype, src, dst, dt, cnt, eid, srcn, dstn, dts);
  k_gather<<<S_TOP / 4, 256, 0, stream>>>(hid, srcn, dstn, Xs, Xg);

  // msg_s = W2s[e]·relu(W1s[e]·xs + b1s) + b2s ; row-dot with p_w -> psb
  k_gemm<0, false><<<GRID_U, 256, 0, stream>>>(Xs, nullptr,
      wbuf + OFF_W1ST, wbuf + OFF_W1ST + 65536, nullptr, nullptr,
      b1s, b1s + 256, B1, cnt, nullptr, nullptr, nullptr, nullptr, nullptr, nullptr);
  k_gemm<1, false><<<GRID_U, 256, 0, stream>>>(B1, nullptr,
      wbuf + OFF_W2ST, wbuf + OFF_W2ST + 65536, nullptr, nullptr,
      b2s, b2s + 256, B2, cnt, p_w, psb, nullptr, nullptr, nullptr, nullptr);
  // msg_g path; a = sigmoid(ps + q-dot + p_b + q_b)
  k_gemm<0, false><<<GRID_U, 256, 0, stream>>>(Xg, nullptr,
      wbuf + OFF_W1GT, wbuf + OFF_W1GT + 65536, nullptr, nullptr,
      b1g, b1g + 256, B1, cnt, nullptr, nullptr, nullptr, nullptr, nullptr, nullptr);
  k_gemm<2, false><<<GRID_U, 256, 0, stream>>>(B1, nullptr,
      wbuf + OFF_W2GT, wbuf + OFF_W2GT + 65536, nullptr, nullptr,
      b2g, b2g + 256, B3, cnt, q_w, psb, aarr, p_b, q_b, nullptr);
  // T = Ms@Ws^T + Ws_b ; X = a*T + (1-a)*(Mg@Wg^T + Wg_b)
  k_gemm<3, false><<<GRID_U, 256, 0, stream>>>(B2, nullptr,
      wbuf + OFF_WST, wbuf + OFF_WST, nullptr, nullptr,
      Ws_b, Ws_b, B1, cnt, nullptr, nullptr, nullptr, nullptr, nullptr, nullptr);
  k_gemm<4, false><<<GRID_U, 256, 0, stream>>>(B3, nullptr,
      wbuf + OFF_WGT, wbuf + OFF_WGT, nullptr, nullptr,
      Wg_b, Wg_b, B4, cnt, nullptr, nullptr, aarr, nullptr, nullptr, B1);
  // gates g: X@Wx[:,g] + Xg@Wh[:,g] + b_lstm[g]
  bf16_t* gbuf[4] = {Xs, B1, B2, B3};
  for (int g = 0; g < 4; ++g) {
    k_gemm<3, true><<<GRID_U, 256, 0, stream>>>(B4, Xg,
        wbuf + OFF_WXT + g * 65536, wbuf + OFF_WXT + g * 65536,
        wbuf + OFF_WHT + g * 65536, wbuf + OFF_WHT + g * 65536,
        b_lstm + g * 256, b_lstm + g * 256, gbuf[g], cnt,
        nullptr, nullptr, nullptr, nullptr, nullptr, nullptr);
  }
  k_lstm<<<S_TOP / 4, 256, 0, stream>>>(gbuf[0], gbuf[1], gbuf[2], gbuf[3],
      cell, eid, dstn, dts, w_out, b_out, decay_w, outS, outH, outC);
}

// Round 2
// 618.336 us; speedup vs baseline: 1.3903x; 1.3903x over previous
//
#include <hip/hip_runtime.h>

// ---------------------------------------------------------------------------
// DyHetGNN forward: grouped-by-etype bf16 MFMA GEMM chain.
// Slots: etype0 rows [0,cnt0), etype1 rows [S_TOP-cnt1, S_TOP); pads garbage.
// ---------------------------------------------------------------------------

#define M_EDGES 32768
#define S_TOP   32896          // M + 128, multiple of 128
#define GRID_U  257            // S_TOP / 128

typedef __bf16 bf16_t;
typedef __bf16 bf16x8 __attribute__((ext_vector_type(8)));
typedef float  f32x4  __attribute__((ext_vector_type(4)));

// weight buffer segment offsets (bf16 elements), all stored [n][k] (k=256 contig)
#define OFF_W1ST 0
#define OFF_W2ST 131072
#define OFF_W1GT 262144
#define OFF_W2GT 393216
#define OFF_WST  524288
#define OFF_WGT  589824
#define OFF_WXT  655360
#define OFF_WHT  917504
#define WBUF_ELEMS 1179648

__device__ __forceinline__ float sigm_f(float x) { return 1.f / (1.f + __expf(-x)); }
__device__ __forceinline__ float tanh_f(float x) {
  x = fminf(fmaxf(x, -15.f), 15.f);
  float e = __expf(2.f * x);
  return (e - 1.f) / (e + 1.f);
}
// XOR swizzle: spreads 128B-stride LDS rows across bank windows (read==write formula)
__device__ __forceinline__ unsigned short* swzp(unsigned short* base, int n, int byteoff) {
  return (unsigned short*)((char*)base + (byteoff ^ ((((n >> 3) ^ n) & 7) << 4)));
}

// ---------------- prep: weight transpose/cast + array init ----------------
__global__ __launch_bounds__(256)
void k_init(const float* __restrict__ W1s, const float* __restrict__ W2s,
            const float* __restrict__ W1g, const float* __restrict__ W2g,
            const float* __restrict__ Wsw, const float* __restrict__ Wgw,
            const float* __restrict__ Wx,  const float* __restrict__ Wh,
            bf16_t* __restrict__ wbuf, int* __restrict__ eid,
            int* __restrict__ srcn, int* __restrict__ dstn,
            float* __restrict__ dts, int* __restrict__ cnt)
{
  const int b = blockIdx.x, tid = threadIdx.x;
  if (b < 256) {                       // 64x64 transpose tiles, fp32 -> bf16
    const float* src; bf16_t* dst; int C_in, n0, k0;
    if (b < 128) {
      const int grp = b >> 5, e = (b >> 4) & 1, t16 = b & 15;
      const float* bases[4] = {W1s, W2s, W1g, W2g};
      src = bases[grp] + e * 65536;
      dst = wbuf + grp * 131072 + e * 65536;
      C_in = 256; n0 = (t16 >> 2) * 64; k0 = (t16 & 3) * 64;
    } else {
      const int b2 = b - 128, mat = b2 >> 6, t64 = b2 & 63;
      src = mat ? Wh : Wx;
      dst = wbuf + OFF_WXT + mat * 262144;
      C_in = 1024; n0 = (t64 >> 2) * 64; k0 = (t64 & 3) * 64;
    }
    __shared__ float tile[64][65];
    const int r = tid >> 2, cg = (tid & 3) * 16;
#pragma unroll
    for (int j = 0; j < 4; ++j) {
      float4 v = *(const float4*)(src + (k0 + r) * C_in + n0 + cg + 4 * j);
      tile[r][cg + 4 * j + 0] = v.x;
      tile[r][cg + 4 * j + 1] = v.y;
      tile[r][cg + 4 * j + 2] = v.z;
      tile[r][cg + 4 * j + 3] = v.w;
    }
    __syncthreads();
    const int c2 = tid >> 2, rg = (tid & 3) * 16;
#pragma unroll
    for (int j = 0; j < 16; ++j)
      dst[(n0 + c2) * 256 + k0 + rg + j] = (bf16_t)tile[rg + j][c2];
  } else {                             // plain casts + defaults
    const int idx0 = (b - 256) * 256 + tid;
    for (int i = idx0; i < 65536; i += 32768) {
      wbuf[OFF_WST + i] = (bf16_t)Wsw[i];   // Ws_w used transposed -> direct cast
      wbuf[OFF_WGT + i] = (bf16_t)Wgw[i];
    }
    for (int i = idx0; i < S_TOP; i += 32768) {
      eid[i] = -1; srcn[i] = 0; dstn[i] = 0; dts[i] = 0.f;
    }
    if (idx0 < 2) cnt[idx0] = 0;
  }
}

// ---------------- slot assignment (wave-aggregated atomics) ----------------
__global__ __launch_bounds__(256)
void k_slots(const int* __restrict__ etype, const int* __restrict__ src,
             const int* __restrict__ dst, const float* __restrict__ dt,
             int* __restrict__ cnt, int* __restrict__ eid, int* __restrict__ srcn,
             int* __restrict__ dstn, float* __restrict__ dts)
{
  const int m = blockIdx.x * 256 + threadIdx.x;      // grid covers M exactly
  const int lane = threadIdx.x & 63;
  const int e = etype[m];
  const unsigned long long b0 = __ballot(e == 0);    // 64-bit wave mask
  const unsigned long long lt = (1ull << lane) - 1;
  const int c0 = __popcll(b0);
  int a0 = 0, a1 = 0;
  if (lane == 0) {
    a0 = atomicAdd(&cnt[0], c0);
    a1 = atomicAdd(&cnt[1], 64 - c0);
  }
  a0 = __shfl(a0, 0);
  a1 = __shfl(a1, 0);
  const int pos = (e == 0) ? (a0 + __popcll(b0 & lt))
                           : (a1 + __popcll(~b0 & lt));
  const int s = (e == 0) ? pos : (S_TOP - 1 - pos);
  eid[s] = m; srcn[s] = src[m]; dstn[s] = dst[m]; dts[s] = dt[m];
}

// ---------------- gather hid rows -> bf16 slot-ordered ----------------
__global__ __launch_bounds__(256)
void k_gather(const float* __restrict__ hid, const int* __restrict__ srcn,
              const int* __restrict__ dstn, bf16_t* __restrict__ Xs,
              bf16_t* __restrict__ Xg)
{
  const int s = blockIdx.x * 4 + (threadIdx.x >> 6);
  const int c = (threadIdx.x & 63) * 4;
  const int ns = srcn[s], ng = dstn[s];
  float4 vs = *(const float4*)(hid + (size_t)ns * 256 + c);
  float4 vg = *(const float4*)(hid + (size_t)ng * 256 + c);
  union { bf16_t h[4]; unsigned long long u; } pk;
  pk.h[0] = (bf16_t)vs.x; pk.h[1] = (bf16_t)vs.y; pk.h[2] = (bf16_t)vs.z; pk.h[3] = (bf16_t)vs.w;
  *(unsigned long long*)(Xs + s * 256 + c) = pk.u;
  pk.h[0] = (bf16_t)vg.x; pk.h[1] = (bf16_t)vg.y; pk.h[2] = (bf16_t)vg.z; pk.h[3] = (bf16_t)vg.w;
  *(unsigned long long*)(Xg + s * 256 + c) = pk.u;
}

// ---------------- unit GEMM: [S_TOP,256] @ [256,256] -------------------
// tile 128x256, 4 waves (each 128 rows x 64 cols), BK=64 LDS-staged B (n-major,
// swizzled), A frags direct from global. EPI: 0 relu, 1 bias+dot->ps,
// 2 bias+dot + a=sigmoid(ps+dot+pb+qb), 3 bias, 4 combine a*T+(1-a)*(acc+b).
template<int EPI, bool DUAL>
__global__ __launch_bounds__(256, 2)
void k_gemm(const bf16_t* __restrict__ A, const bf16_t* __restrict__ A2,
            const bf16_t* __restrict__ W0, const bf16_t* __restrict__ W1,
            const bf16_t* __restrict__ W20, const bf16_t* __restrict__ W21,
            const float* __restrict__ bias0, const float* __restrict__ bias1,
            bf16_t* __restrict__ Out, const int* __restrict__ cnt,
            const float* __restrict__ pq, float* __restrict__ ps,
            float* __restrict__ aarr, const float* __restrict__ sb0,
            const float* __restrict__ sb1, const bf16_t* __restrict__ Tmat)
{
  const int tid = threadIdx.x;
  const int w = tid >> 6, lane = tid & 63, lo = lane & 15, hi = lane >> 4;
  const int row0 = blockIdx.x * 128;
  const int cnt0 = cnt[0], cnt1 = cnt[1];
  const int cnt0r = (cnt0 + 127) & ~127;
  const int v1 = S_TOP - cnt1;
  if (row0 >= cnt0r && row0 + 128 <= v1) return;   // fully-dead block
  const int e = (row0 < cnt0r) ? 0 : 1;
  const float* bias = e ? bias1 : bias0;

  __shared__ unsigned short Bt[256 * 64];   // [n=256][kk=64] bf16, 32 KiB
  __shared__ float sdot[128];

  f32x4 acc[8][4];
  const f32x4 z4 = {0.f, 0.f, 0.f, 0.f};
#pragma unroll
  for (int rb = 0; rb < 8; ++rb)
#pragma unroll
    for (int tc = 0; tc < 4; ++tc) acc[rb][tc] = z4;

  const int nph = DUAL ? 2 : 1;
  for (int ph = 0; ph < nph; ++ph) {
    const bf16_t* Ap = (DUAL && ph) ? A2 : A;
    const bf16_t* Wp = (DUAL && ph) ? (e ? W21 : W20) : (e ? W1 : W0);
    for (int c = 0; c < 4; ++c) {               // K chunks of 64
      __syncthreads();
#pragma unroll
      for (int p = 0; p < 4; ++p) {             // stage B chunk
        const int n = (tid >> 2) + p * 64;
        const int i0 = tid & 3;
        const bf16_t* sp = Wp + n * 256 + c * 64;
        bf16x8 v0 = *(const bf16x8*)(sp + i0 * 8);
        bf16x8 v1 = *(const bf16x8*)(sp + 32 + i0 * 8);
        *(bf16x8*)swzp(Bt, n, n * 128 + i0 * 16) = v0;
        *(bf16x8*)swzp(Bt, n, n * 128 + 64 + i0 * 16) = v1;
      }
      __syncthreads();
#pragma unroll
      for (int ks = 0; ks < 2; ++ks) {          // two K=32 steps
        bf16x8 af[8];
#pragma unroll
        for (int rb = 0; rb < 8; ++rb)
          af[rb] = *(const bf16x8*)(Ap + (row0 + rb * 16 + lo) * 256 + c * 64 + ks * 32 + hi * 8);
#pragma unroll
        for (int tc = 0; tc < 4; ++tc) {
          const int n = w * 64 + tc * 16 + lo;
          bf16x8 bf = *(const bf16x8*)swzp(Bt, n, n * 128 + ks * 64 + hi * 16);
#pragma unroll
          for (int rb = 0; rb < 8; ++rb)
            acc[rb][tc] = __builtin_amdgcn_mfma_f32_16x16x32_bf16(af[rb], bf, acc[rb][tc], 0, 0, 0);
        }
      }
    }
  }

  if (EPI == 1 || EPI == 2) {
    if (tid < 128) sdot[tid] = 0.f;
    __syncthreads();
  }

  float dots[8][4];
#pragma unroll
  for (int rb = 0; rb < 8; ++rb)
#pragma unroll
    for (int i = 0; i < 4; ++i) dots[rb][i] = 0.f;

#pragma unroll
  for (int rb = 0; rb < 8; ++rb) {
#pragma unroll
    for (int tc = 0; tc < 4; ++tc) {
      const int col = w * 64 + tc * 16 + lo;
      const float bs = bias[col];
      const float pqv = (EPI == 1 || EPI == 2) ? pq[col] : 0.f;
      f32x4 v = acc[rb][tc];
#pragma unroll
      for (int i = 0; i < 4; ++i) {
        const int row = row0 + rb * 16 + hi * 4 + i;
        float val = v[i] + bs;
        if (EPI == 0) val = fmaxf(val, 0.f);
        if (EPI == 4) {
          const float av = aarr[row];
          const float tv = (float)Tmat[row * 256 + col];
          val = av * tv + (1.f - av) * val;
        }
        if (EPI == 1 || EPI == 2) dots[rb][i] += val * pqv;
        Out[row * 256 + col] = (bf16_t)val;
      }
    }
  }

  if (EPI == 1 || EPI == 2) {
#pragma unroll
    for (int rb = 0; rb < 8; ++rb) {
#pragma unroll
      for (int i = 0; i < 4; ++i) {
        float d = dots[rb][i];
        d += __shfl_xor(d, 1); d += __shfl_xor(d, 2);
        d += __shfl_xor(d, 4); d += __shfl_xor(d, 8);
        if (lo == 0) atomicAdd(&sdot[rb * 16 + hi * 4 + i], d);
      }
    }
    __syncthreads();
    if (tid < 128) {
      const int row = row0 + tid;
      if (EPI == 1) ps[row] = sdot[tid];
      else          aarr[row] = sigm_f(ps[row] + sdot[tid] + sb0[0] + sb1[0]);
    }
  }
}

// ---------------- elementwise LSTM + score (wave per row) ----------------
__global__ __launch_bounds__(256)
void k_lstm(const bf16_t* __restrict__ Gi, const bf16_t* __restrict__ Gf,
            const bf16_t* __restrict__ Gg, const bf16_t* __restrict__ Go,
            const float* __restrict__ cell, const int* __restrict__ eid,
            const int* __restrict__ dstn, const float* __restrict__ dts,
            const float* __restrict__ w_out, const float* __restrict__ b_out,
            const float* __restrict__ decay_w,
            float* __restrict__ outS, float* __restrict__ outH, float* __restrict__ outC)
{
  const int s = blockIdx.x * 4 + (threadIdx.x >> 6);
  const int lane = threadIdx.x & 63;
  const int m = eid[s];
  const int nd = dstn[s];
  const float dec = __expf(-fabsf(decay_w[0]) * dts[s]);
  float part = 0.f;
#pragma unroll
  for (int j = 0; j < 4; ++j) {
    const int cdim = j * 64 + lane;
    const float iv = (float)Gi[s * 256 + cdim];
    const float fv = (float)Gf[s * 256 + cdim];
    const float gv = (float)Gg[s * 256 + cdim];
    const float ov = (float)Go[s * 256 + cdim];
    const float cg = cell[(size_t)nd * 256 + cdim];
    const float cn = sigm_f(fv) * (cg * dec) + sigm_f(iv) * tanh_f(gv);
    const float hn = sigm_f(ov) * tanh_f(cn);
    if (m >= 0) {
      outH[(size_t)m * 256 + cdim] = hn;
      outC[(size_t)m * 256 + cdim] = cn;
    }
    part += hn * w_out[cdim];
  }
#pragma unroll
  for (int msk = 1; msk < 64; msk <<= 1) part += __shfl_xor(part, msk);
  if (lane == 0 && m >= 0) outS[m] = sigm_f(part + b_out[0]);
}

// ---------------------------------------------------------------------------
extern "C" void kernel_launch(void* const* d_in, const int* in_sizes, int n_in,
                              void* d_out, int out_size, void* d_ws, size_t ws_size,
                              hipStream_t stream)
{
  const int*   src     = (const int*)d_in[0];
  const int*   dst     = (const int*)d_in[1];
  const int*   etype   = (const int*)d_in[2];
  const float* dt      = (const float*)d_in[3];
  const float* hid     = (const float*)d_in[4];
  const float* cell    = (const float*)d_in[5];
  const float* W1s     = (const float*)d_in[6];
  const float* b1s     = (const float*)d_in[7];
  const float* W2s     = (const float*)d_in[8];
  const float* b2s     = (const float*)d_in[9];
  const float* W1g     = (const float*)d_in[10];
  const float* b1g     = (const float*)d_in[11];
  const float* W2g     = (const float*)d_in[12];
  const float* b2g     = (const float*)d_in[13];
  const float* p_w     = (const float*)d_in[14];
  const float* p_b     = (const float*)d_in[15];
  const float* q_w     = (const float*)d_in[16];
  const float* q_b     = (const float*)d_in[17];
  const float* Ws_w    = (const float*)d_in[18];
  const float* Ws_b    = (const float*)d_in[19];
  const float* Wg_w    = (const float*)d_in[20];
  const float* Wg_b    = (const float*)d_in[21];
  const float* Wx      = (const float*)d_in[22];
  const float* Wh      = (const float*)d_in[23];
  const float* b_lstm  = (const float*)d_in[24];
  const float* w_out   = (const float*)d_in[25];
  const float* b_out   = (const float*)d_in[26];
  const float* decay_w = (const float*)d_in[27];
  (void)in_sizes; (void)n_in; (void)out_size; (void)ws_size;

  char* p = (char*)d_ws;
  auto alloc = [&](size_t bytes) { char* r = p; p += (bytes + 255) & ~(size_t)255; return r; };
  const size_t SB = (size_t)S_TOP * 256 * sizeof(bf16_t);
  bf16_t* wbuf = (bf16_t*)alloc(WBUF_ELEMS * sizeof(bf16_t));
  bf16_t* Xs   = (bf16_t*)alloc(SB);
  bf16_t* Xg   = (bf16_t*)alloc(SB);
  bf16_t* B1   = (bf16_t*)alloc(SB);
  bf16_t* B2   = (bf16_t*)alloc(SB);
  bf16_t* B3   = (bf16_t*)alloc(SB);
  bf16_t* B4   = (bf16_t*)alloc(SB);
  float*  psb  = (float*)alloc(S_TOP * 4);
  float*  aarr = (float*)alloc(S_TOP * 4);
  int*    eid  = (int*)alloc(S_TOP * 4);
  int*    srcn = (int*)alloc(S_TOP * 4);
  int*    dstn = (int*)alloc(S_TOP * 4);
  float*  dts  = (float*)alloc(S_TOP * 4);
  int*    cnt  = (int*)alloc(256);
  // total ws use ~100 MiB

  float* outS = (float*)d_out;
  float* outH = outS + M_EDGES;
  float* outC = outH + (size_t)M_EDGES * 256;

  k_init<<<384, 256, 0, stream>>>(W1s, W2s, W1g, W2g, Ws_w, Wg_w, Wx, Wh,
                                  wbuf, eid, srcn, dstn, dts, cnt);
  k_slots<<<M_EDGES / 256, 256, 0, stream>>>(etype, src, dst, dt, cnt, eid, srcn, dstn, dts);
  k_gather<<<S_TOP / 4, 256, 0, stream>>>(hid, srcn, dstn, Xs, Xg);

  // msg_s = W2s[e]·relu(W1s[e]·xs + b1s) + b2s ; row-dot with p_w -> psb
  k_gemm<0, false><<<GRID_U, 256, 0, stream>>>(Xs, nullptr,
      wbuf + OFF_W1ST, wbuf + OFF_W1ST + 65536, nullptr, nullptr,
      b1s, b1s + 256, B1, cnt, nullptr, nullptr, nullptr, nullptr, nullptr, nullptr);
  k_gemm<1, false><<<GRID_U, 256, 0, stream>>>(B1, nullptr,
      wbuf + OFF_W2ST, wbuf + OFF_W2ST + 65536, nullptr, nullptr,
      b2s, b2s + 256, B2, cnt, p_w, psb, nullptr, nullptr, nullptr, nullptr);
  // msg_g path; a = sigmoid(ps + q-dot + p_b + q_b)
  k_gemm<0, false><<<GRID_U, 256, 0, stream>>>(Xg, nullptr,
      wbuf + OFF_W1GT, wbuf + OFF_W1GT + 65536, nullptr, nullptr,
      b1g, b1g + 256, B1, cnt, nullptr, nullptr, nullptr, nullptr, nullptr, nullptr);
  k_gemm<2, false><<<GRID_U, 256, 0, stream>>>(B1, nullptr,
      wbuf + OFF_W2GT, wbuf + OFF_W2GT + 65536, nullptr, nullptr,
      b2g, b2g + 256, B3, cnt, q_w, psb, aarr, p_b, q_b, nullptr);
  // T = Ms@Ws^T + Ws_b ; X = a*T + (1-a)*(Mg@Wg^T + Wg_b)
  k_gemm<3, false><<<GRID_U, 256, 0, stream>>>(B2, nullptr,
      wbuf + OFF_WST, wbuf + OFF_WST, nullptr, nullptr,
      Ws_b, Ws_b, B1, cnt, nullptr, nullptr, nullptr, nullptr, nullptr, nullptr);
  k_gemm<4, false><<<GRID_U, 256, 0, stream>>>(B3, nullptr,
      wbuf + OFF_WGT, wbuf + OFF_WGT, nullptr, nullptr,
      Wg_b, Wg_b, B4, cnt, nullptr, nullptr, aarr, nullptr, nullptr, B1);
  // gates g: X@Wx[:,g] + Xg@Wh[:,g] + b_lstm[g]
  bf16_t* gbuf[4] = {Xs, B1, B2, B3};
  for (int g = 0; g < 4; ++g) {
    k_gemm<3, true><<<GRID_U, 256, 0, stream>>>(B4, Xg,
        wbuf + OFF_WXT + g * 65536, wbuf + OFF_WXT + g * 65536,
        wbuf + OFF_WHT + g * 65536, wbuf + OFF_WHT + g * 65536,
        b_lstm + g * 256, b_lstm + g * 256, gbuf[g], cnt,
        nullptr, nullptr, nullptr, nullptr, nullptr, nullptr);
  }
  k_lstm<<<S_TOP / 4, 256, 0, stream>>>(gbuf[0], gbuf[1], gbuf[2], gbuf[3],
      cell, eid, dstn, dts, w_out, b_out, decay_w, outS, outH, outC);
}